// Round 11
// baseline (320.524 us; speedup 1.0000x reference)
//
#include <hip/hip_runtime.h>
#include <hip/hip_fp16.h>
#include <stdint.h>

// out[b,o] = sum_{l,i} lookups[b,l]*values[b,i]*W[l,i,o] + sum_l lookups[b,l]*bias[l,o]
// GEMM M=65536, K=65 tiles of 64 (i-chunk outer, l inner; tile 64 = bias), N=256.
// v5b: minimal-VALU free-flow loop. Fix vs v5: ks1 LDS offsets precomputed with
// XOR applied AFTER the +64B k-offset ((base+64)^swz != (base^swz)+64).

#define B_TOK 65536
#define L_DIM 16
#define I_DIM 256
#define O_DIM 256
#define BM    256
#define THREADS 512

// LDS: [0,32K) B buf0 | [32K,64K) B buf1 | [64K,96K) A chunk (XOR-swizzled)
//      [96K, +18432) lkh: [256 rows][18 slots] half2{lk,lk} (16 used)
#define AOFF   65536
#define LKOFF  98304
#define LKROWB 72
#define SMEMSZ 116736

typedef __attribute__((ext_vector_type(8))) _Float16 f16x8;
typedef __attribute__((ext_vector_type(4))) float f32x4;
typedef __attribute__((address_space(3))) void      lds_void_t;
typedef const __attribute__((address_space(1))) void gbl_void_t;

static __device__ __forceinline__ f16x8 scale8(f16x8 a, __half2 s) {
    union { f16x8 v; __half2 h[4]; } u; u.v = a;
#pragma unroll
    for (int q = 0; q < 4; ++q) u.h[q] = __hmul2(u.h[q], s);
    return u.v;
}

// ---------------------------------------------------------------------------
// prep_w: Wst = 65 tiles x 32KB fp16, [o][kk] (B-transposed), pre-swizzled:
// 16B chunk at position cp holds kk-group c = cp ^ (o&7).
// ---------------------------------------------------------------------------
__global__ void prep_w(const float* __restrict__ W, const float* __restrict__ bias,
                       unsigned short* __restrict__ ws) {
    const int t  = blockIdx.x;
    const int o  = blockIdx.y * 32 + (threadIdx.x & 31);
    const int cp = threadIdx.x >> 5;
    const int c  = cp ^ (o & 7);
    uint32_t p[4];
    if (t < 64) {
        const int l = t & 15, ibase = (t >> 4) * 64;
        const float* src = W + ((size_t)l * I_DIM + ibase + c * 8) * O_DIM + o;
#pragma unroll
        for (int jp = 0; jp < 4; ++jp) {
            float a = src[(size_t)(2 * jp) * O_DIM];
            float b = src[(size_t)(2 * jp + 1) * O_DIM];
            p[jp] = __builtin_bit_cast(uint32_t, __floats2half2_rn(a, b));
        }
    } else if (c < 2) {
#pragma unroll
        for (int jp = 0; jp < 4; ++jp) {
            int kk = c * 8 + 2 * jp;
            float a = bias[(size_t)kk * O_DIM + o];
            float b = bias[(size_t)(kk + 1) * O_DIM + o];
            p[jp] = __builtin_bit_cast(uint32_t, __floats2half2_rn(a, b));
        }
    } else {
        p[0] = p[1] = p[2] = p[3] = 0u;
    }
    uint4 q = {p[0], p[1], p[2], p[3]};
    *(uint4*)((char*)ws + (size_t)t * 32768 + o * 128 + cp * 16) = q;
}

// ---------------------------------------------------------------------------
__launch_bounds__(THREADS, 2)
__global__ void md_gemm(const float* __restrict__ lookups,        // [B][16]
                        const float* __restrict__ values,         // [B][256]
                        const unsigned short* __restrict__ Wst,   // [65][16384]
                        float* __restrict__ out) {                // [B][256]
    __shared__ char smem[SMEMSZ];

    const int tid  = threadIdx.x;
    const int wid  = tid >> 6;
    const int lane = tid & 63;
    const int row0 = blockIdx.x * BM;

    const int r = tid >> 1;          // staging row 0..255
    const int h = tid & 1;           // staging k-half

    const int wm   = wid >> 2;       // 0..1
    const int wn   = wid & 3;        // 0..3
    const int arow = wm * 128 + (lane & 15);
    const int bcol = wn * 64  + (lane & 15);
    const int kkl  = (lane >> 4) * 8;

    // ---- precomputed swizzled LDS byte offsets (ks0 and ks1 separately!) ----
    uint32_t oA[8], oA1[8], oB[4], oB1[4];
#pragma unroll
    for (int mt = 0; mt < 8; ++mt) {
        int row = arow + mt * 16, swz = (row & 7) << 4, base = row * 128 + kkl * 2;
        oA[mt]  = AOFF + (uint32_t)(base ^ swz);
        oA1[mt] = AOFF + (uint32_t)((base + 64) ^ swz);   // ks1: +32 halves, XOR after
    }
#pragma unroll
    for (int nt = 0; nt < 4; ++nt) {
        int o = bcol + nt * 16, swz = (o & 7) << 4, base = o * 128 + kkl * 2;
        oB[nt]  = (uint32_t)(base ^ swz);
        oB1[nt] = (uint32_t)((base + 64) ^ swz);
    }
    const uint32_t oL = LKOFF + (uint32_t)arow * LKROWB;

    f32x4 acc[8][4];
#pragma unroll
    for (int m = 0; m < 8; ++m)
#pragma unroll
        for (int n = 0; n < 4; ++n) acc[m][n] = (f32x4){0.f, 0.f, 0.f, 0.f};

    // stage all 4 gload_lds slices of B-tile g into buffer nb (nb literal at call)
    auto stage1 = [&](int g, int nb) {
        const char* src = (const char*)Wst + (size_t)g * 32768 + wid * 1024 + lane * 16;
#pragma unroll
        for (int s = 0; s < 4; ++s)
            __builtin_amdgcn_global_load_lds(
                (gbl_void_t*)(src + s * 8192),
                (lds_void_t*)&smem[nb * 32768 + wid * 1024 + s * 8192], 16, 0, 0);
    };

    // stage unscaled fp16 values chunk cc into A-LDS (XOR-swizzled)
    auto stageA = [&](int cc) {
        const float4* vp = (const float4*)(values + (size_t)(row0 + r) * I_DIM
                                           + cc * 64 + h * 32);
        uint32_t p[16];
#pragma unroll
        for (int j = 0; j < 8; ++j) {
            float4 f = vp[j];
            p[2 * j]     = __builtin_bit_cast(uint32_t, __floats2half2_rn(f.x, f.y));
            p[2 * j + 1] = __builtin_bit_cast(uint32_t, __floats2half2_rn(f.z, f.w));
        }
#pragma unroll
        for (int w = 0; w < 4; ++w) {
            uint4 q = {p[4 * w], p[4 * w + 1], p[4 * w + 2], p[4 * w + 3]};
            *(uint4*)&smem[AOFF + ((r * 128 + h * 64 + w * 16) ^ ((r & 7) << 4))] = q;
        }
    };

    auto stageA_bias = [&]() {    // A = lookups (fp16, from lkh) in kk<16, zeros else
        uint32_t p[16];
#pragma unroll
        for (int j = 0; j < 16; ++j) p[j] = 0u;
        if (h == 0) {
            const __half* hp = (const __half*)&smem[LKOFF + r * LKROWB];
#pragma unroll
            for (int j = 0; j < 8; ++j) {
                __half2 d; d.x = hp[4 * j]; d.y = hp[4 * j + 2];
                p[j] = __builtin_bit_cast(uint32_t, d);
            }
        }
#pragma unroll
        for (int w = 0; w < 4; ++w) {
            uint4 q = {p[4 * w], p[4 * w + 1], p[4 * w + 2], p[4 * w + 3]};
            *(uint4*)&smem[AOFF + ((r * 128 + h * 64 + w * 16) ^ ((r & 7) << 4))] = q;
        }
    };

    // ---- prologue: lkh (pre-dup half2), B(0)->buf0, A chunk0 ----
    {
        const float4* lp = (const float4*)(lookups + (size_t)(row0 + r) * L_DIM + h * 8);
        float4 f0 = lp[0], f1 = lp[1];
        float v[8] = {f0.x, f0.y, f0.z, f0.w, f1.x, f1.y, f1.z, f1.w};
#pragma unroll
        for (int j = 0; j < 8; ++j) {
            __half hv = __float2half(v[j]);
            __half2 d; d.x = hv; d.y = hv;
            *(uint32_t*)&smem[LKOFF + r * LKROWB + (h * 8 + j) * 4] =
                __builtin_bit_cast(uint32_t, d);
        }
    }
    stage1(0, 0);
    stageA(0);
    __syncthreads();   // drains gloads + ds_writes; lkh/A/B0 visible

    f16x8 afk0[8];     // ks0 A-fragments, resident per chunk
#pragma unroll
    for (int mt = 0; mt < 8; ++mt)
        afk0[mt] = *(const f16x8*)&smem[oA[mt]];

    uint32_t lkA[8], lkB[8];   // half2{lk,lk} per mt, double-buffered across tiles
#pragma unroll
    for (int mt = 0; mt < 8; ++mt)
        lkA[mt] = *(const uint32_t*)&smem[oL + mt * 1152];   // l=0

    // ---- main loop: 64 tiles, unroll x2 for compile-time buffer parity ----
    auto body = [&](int kt, const int BUF, uint32_t (&cur)[8], uint32_t (&nxt)[8]) {
        stage1(kt + 1, 1 - BUF);            // early-issue next B tile (4 gloads)
        {                                    // prefetch next tile's lk (no VALU)
            uint32_t ol = oL + (uint32_t)(((kt + 1) & 15) << 2);
#pragma unroll
            for (int mt = 0; mt < 8; ++mt)
                nxt[mt] = *(const uint32_t*)&smem[ol + mt * 1152];
        }
        // Ph0: ks0 (A resident)
        f16x8 b0[4];
#pragma unroll
        for (int nt = 0; nt < 4; ++nt)
            b0[nt] = *(const f16x8*)&smem[oB[nt] + BUF * 32768];
#pragma unroll
        for (int m = 0; m < 8; ++m) {
            f16x8 a = scale8(afk0[m], __builtin_bit_cast(__half2, cur[m]));
#pragma unroll
            for (int nt = 0; nt < 4; ++nt)
                acc[m][nt] = __builtin_amdgcn_mfma_f32_16x16x32_f16(a, b0[nt],
                                                                    acc[m][nt], 0, 0, 0);
        }
        // Ph1: ks1 (A streamed)
        f16x8 b1[4];
#pragma unroll
        for (int nt = 0; nt < 4; ++nt)
            b1[nt] = *(const f16x8*)&smem[oB1[nt] + BUF * 32768];
#pragma unroll
        for (int m = 0; m < 8; ++m) {
            f16x8 a1 = *(const f16x8*)&smem[oA1[m]];
            a1 = scale8(a1, __builtin_bit_cast(__half2, cur[m]));
#pragma unroll
            for (int nt = 0; nt < 4; ++nt)
                acc[m][nt] = __builtin_amdgcn_mfma_f32_16x16x32_f16(a1, b1[nt],
                                                                    acc[m][nt], 0, 0, 0);
        }
        if ((kt & 15) == 15) {               // chunk boundary (4x per kernel)
            __syncthreads();                 // all reads of old A done; drains vmcnt
            if (kt < 63) stageA((kt >> 4) + 1); else stageA_bias();
            __syncthreads();                 // new A visible
#pragma unroll
            for (int mt = 0; mt < 8; ++mt)
                afk0[mt] = *(const f16x8*)&smem[oA[mt]];
        } else {
            // B(kt+1) issued at tile top (~full tile ago) -> near-free drain
            asm volatile("s_waitcnt vmcnt(0)\n\ts_barrier" ::: "memory");
        }
    };

    for (int kt2 = 0; kt2 < 64; kt2 += 2) {
        body(kt2,     0, lkA, lkB);
        body(kt2 + 1, 1, lkB, lkA);
    }

    // ---- bias tile kt=64 (buf0; only kk<16 nonzero -> ks0 only, no scaling) ----
    {
        f16x8 b0[4];
#pragma unroll
        for (int nt = 0; nt < 4; ++nt)
            b0[nt] = *(const f16x8*)&smem[oB[nt]];
#pragma unroll
        for (int m = 0; m < 8; ++m)
#pragma unroll
            for (int nt = 0; nt < 4; ++nt)
                acc[m][nt] = __builtin_amdgcn_mfma_f32_16x16x32_f16(afk0[m], b0[nt],
                                                                    acc[m][nt], 0, 0, 0);
    }

    // ---- epilogue: C/D layout col=lane&15, row=(lane>>4)*4+j ----
    const int orow = row0 + wm * 128 + (lane >> 4) * 4;
    const int ocol = wn * 64 + (lane & 15);
#pragma unroll
    for (int mt = 0; mt < 8; ++mt)
#pragma unroll
        for (int nt = 0; nt < 4; ++nt) {
#pragma unroll
            for (int j = 0; j < 4; ++j)
                out[(size_t)(orow + mt * 16 + j) * O_DIM + ocol + nt * 16] = acc[mt][nt][j];
        }
}

extern "C" void kernel_launch(void* const* d_in, const int* in_sizes, int n_in,
                              void* d_out, int out_size, void* d_ws, size_t ws_size,
                              hipStream_t stream) {
    const float* lookups = (const float*)d_in[0];
    const float* values  = (const float*)d_in[1];
    const float* W       = (const float*)d_in[2];
    const float* bias    = (const float*)d_in[3];
    unsigned short* Wst  = (unsigned short*)d_ws;   // 65*32768 B = 2.08 MB

    prep_w<<<dim3(65, 8), dim3(256), 0, stream>>>(W, bias, Wst);
    md_gemm<<<dim3(B_TOK / BM), dim3(THREADS), 0, stream>>>(lookups, values, Wst,
                                                            (float*)d_out);
}